// Round 9
// baseline (97.429 us; speedup 1.0000x reference)
//
#include <hip/hip_runtime.h>

// LatencyEncoder R8 = R7 (two-kernel, grid-stride store order: 85->79.7us)
// with K2 occupancy/window tuning + load pipelining.
//  - R7 K2 ran 32 waves/CU (8.4 MB instantaneous window, 32 interleaved
//    streams/CU); rocclr fill (6.85 TB/s reference) runs ~3.5 waves/CU with
//    a ~1 MB dense window. K2' uses 512 blocks = 8 waves/CU (2 MB window).
//  - The per-iteration u8 lat load fed the store directly (dependent chain);
//    now software-pipelined one iteration ahead so stores never wait on it.
//  - K1 unchanged: f64 decision chain matches numpy ref bit-exactly
//    (absmax 0.0 in every passing round); u8 table in d_ws.
//  - Fallback single-kernel path if ws_size < npairs (correctness safety).

#define T 100

typedef float vf4 __attribute__((ext_vector_type(4)));

__device__ __forceinline__ int pair_latency_f64(float xv, float nv) {
  double xn = (double)xv + (double)nv * 0.01;
  double s = 1.0 / (1.0 + exp(-xn));
  int li = (int)rint((1.0 - s) * 99.0);
  li = li < 0 ? 0 : (li > 99 ? 99 : li);
  return (s > 0.5) ? li : 255;  // 255: no spike
}

__global__ __launch_bounds__(256) void lat_kernel(
    const float* __restrict__ x, const float* __restrict__ noise,
    unsigned char* __restrict__ lat, int npairs) {
  const int stride = gridDim.x * 256;
  for (int p = blockIdx.x * 256 + threadIdx.x; p < npairs; p += stride)
    lat[p] = (unsigned char)pair_latency_f64(x[p], noise[p]);
}

__global__ __launch_bounds__(256) void onehot_stream_kernel(
    const unsigned char* __restrict__ lat, vf4* __restrict__ o4, int n4) {
  const int stride = gridDim.x * 256;  // 131,072
  int i = blockIdx.x * 256 + threadIdx.x;
  if (i >= n4) return;

  // pipeline stage 0: current iteration's latency
  int pair = i / 25;
  int L = lat[pair];
  int pos = (i - pair * 25) * 4;

  for (;;) {
    const int inext = i + stride;
    const bool have = inext < n4;
    // prefetch next iteration's latency before the store (hides L1/L2 hit)
    int Ln = 0, posn = 0;
    if (have) {
      const int pn = inext / 25;
      Ln = lat[pn];
      posn = (inext - pn * 25) * 4;
    }
    vf4 v;
    v.x = (L == pos + 0) ? 1.0f : 0.0f;
    v.y = (L == pos + 1) ? 1.0f : 0.0f;
    v.z = (L == pos + 2) ? 1.0f : 0.0f;
    v.w = (L == pos + 3) ? 1.0f : 0.0f;
    o4[i] = v;
    if (!have) break;
    i = inext; L = Ln; pos = posn;
  }
}

// ---- fallback (R0 structure) if d_ws is too small ----
__global__ __launch_bounds__(256) void latency_encode_fused(
    const float* __restrict__ x, const float* __restrict__ noise,
    float* __restrict__ out, int npairs) {
  __shared__ int lat_s[256];
  const int tid = threadIdx.x;
  const int pairBase = blockIdx.x * 256;
  const int p = pairBase + tid;
  int lat = 255;
  if (p < npairs) lat = pair_latency_f64(x[p], noise[p]);
  lat_s[tid] = lat;
  __syncthreads();
  vf4* o4 = (vf4*)(out + (size_t)pairBase * T);
#pragma unroll
  for (int k = 0; k < 25; ++k) {
    const int fi4 = tid + k * 256;
    const int pl = fi4 / 25;
    const int pos = (fi4 % 25) * 4;
    const int L = lat_s[pl];
    vf4 v;
    v.x = (L == pos + 0) ? 1.0f : 0.0f;
    v.y = (L == pos + 1) ? 1.0f : 0.0f;
    v.z = (L == pos + 2) ? 1.0f : 0.0f;
    v.w = (L == pos + 3) ? 1.0f : 0.0f;
    if (pairBase + pl < npairs) o4[fi4] = v;
  }
}

extern "C" void kernel_launch(void* const* d_in, const int* in_sizes, int n_in,
                              void* d_out, int out_size, void* d_ws, size_t ws_size,
                              hipStream_t stream) {
  const float* x = (const float*)d_in[0];
  const float* noise = (const float*)d_in[1];
  float* out = (float*)d_out;
  const int npairs = in_sizes[0];  // 1,048,576

  if (ws_size >= (size_t)npairs) {
    unsigned char* lat = (unsigned char*)d_ws;
    lat_kernel<<<1024, 256, 0, stream>>>(x, noise, lat, npairs);
    const int n4 = out_size / 4;  // 26,214,400
    onehot_stream_kernel<<<512, 256, 0, stream>>>(lat, (vf4*)out, n4);
  } else {
    const int grid = (npairs + 255) / 256;
    latency_encode_fused<<<grid, 256, 0, stream>>>(x, noise, out, npairs);
  }
}

// Round 10
// 81.146 us; speedup vs baseline: 1.2007x; 1.2007x over previous
//
#include <hip/hip_runtime.h>

// LatencyEncoder R9 = R7 (79.7us: two-kernel, grid-stride store order) with a
// cheap K1. R8 lesson: K2 needs max residency + simple loop -> K2 is
// byte-identical to R7 (2048 blocks). K1 changes:
//  - spike decision s>0.5 <=> xn>0, EXACT in f64 with one mul+add (no exp);
//    ~50% of pairs skip all transcendentals.
//  - bucket via f32: l = 99/(1+expf(xn)); accepted when rint-distance is
//    >5e-4 from the 0.5 boundary (f32 vs f64 chain discrepancy bounded ~2e-5,
//    25x margin). Borderline (~0.1%) redo the canonical f64 chain -> decisions
//    match the numpy reference exactly (absmax 0.0 in all passing rounds).
//  - float4 loads / uchar4 table stores.

#define T 100

typedef float vf4 __attribute__((ext_vector_type(4)));

__device__ __forceinline__ unsigned char lat_one(float xf, float nf) {
  const double xn = (double)xf + (double)nf * 0.01;
  if (!(xn > 0.0)) return 255;  // exact spike decision: s>0.5 <=> xn>0
  const float l = 99.0f / (1.0f + __expf((float)xn));  // = 99*(1-sigmoid)
  const float r = rintf(l);
  int li;
  if (fabsf(l - r) > 0.4995f) {
    // borderline: canonical f64 chain (bit-matches np reference)
    const double s = 1.0 / (1.0 + exp(-xn));
    li = (int)rint((1.0 - s) * 99.0);
  } else {
    li = (int)r;
  }
  li = li < 0 ? 0 : (li > 99 ? 99 : li);
  return (unsigned char)li;
}

__global__ __launch_bounds__(256) void lat_kernel_v4(
    const float4* __restrict__ x4, const float4* __restrict__ n4,
    uchar4* __restrict__ lat4, int nquads) {
  const int stride = gridDim.x * 256;
  for (int q = blockIdx.x * 256 + threadIdx.x; q < nquads; q += stride) {
    const float4 xv = x4[q], nv = n4[q];
    uchar4 r;
    r.x = lat_one(xv.x, nv.x);
    r.y = lat_one(xv.y, nv.y);
    r.z = lat_one(xv.z, nv.z);
    r.w = lat_one(xv.w, nv.w);
    lat4[q] = r;
  }
}

__global__ __launch_bounds__(256) void lat_kernel_scalar(
    const float* __restrict__ x, const float* __restrict__ noise,
    unsigned char* __restrict__ lat, int npairs) {
  const int stride = gridDim.x * 256;
  for (int p = blockIdx.x * 256 + threadIdx.x; p < npairs; p += stride)
    lat[p] = lat_one(x[p], noise[p]);
}

// K2: byte-identical to R7 (best measured store config).
__global__ __launch_bounds__(256) void onehot_stream_kernel(
    const unsigned char* __restrict__ lat, vf4* __restrict__ o4, int n4) {
  const int stride = gridDim.x * 256;
  for (int i = blockIdx.x * 256 + threadIdx.x; i < n4; i += stride) {
    const int pair = i / 25;
    const int pos = (i - pair * 25) * 4;
    const int L = lat[pair];
    vf4 v;
    v.x = (L == pos + 0) ? 1.0f : 0.0f;
    v.y = (L == pos + 1) ? 1.0f : 0.0f;
    v.z = (L == pos + 2) ? 1.0f : 0.0f;
    v.w = (L == pos + 3) ? 1.0f : 0.0f;
    o4[i] = v;
  }
}

// ---- fallback (R0 structure, full f64) if d_ws is too small ----
__global__ __launch_bounds__(256) void latency_encode_fused(
    const float* __restrict__ x, const float* __restrict__ noise,
    float* __restrict__ out, int npairs) {
  __shared__ int lat_s[256];
  const int tid = threadIdx.x;
  const int pairBase = blockIdx.x * 256;
  const int p = pairBase + tid;
  int lat = 255;
  if (p < npairs) {
    double xn = (double)x[p] + (double)noise[p] * 0.01;
    double s = 1.0 / (1.0 + exp(-xn));
    if (s > 0.5) {
      int li = (int)rint((1.0 - s) * 99.0);
      lat = li < 0 ? 0 : (li > 99 ? 99 : li);
    }
  }
  lat_s[tid] = lat;
  __syncthreads();
  vf4* o4 = (vf4*)(out + (size_t)pairBase * T);
#pragma unroll
  for (int k = 0; k < 25; ++k) {
    const int fi4 = tid + k * 256;
    const int pl = fi4 / 25;
    const int pos = (fi4 % 25) * 4;
    const int L = lat_s[pl];
    vf4 v;
    v.x = (L == pos + 0) ? 1.0f : 0.0f;
    v.y = (L == pos + 1) ? 1.0f : 0.0f;
    v.z = (L == pos + 2) ? 1.0f : 0.0f;
    v.w = (L == pos + 3) ? 1.0f : 0.0f;
    if (pairBase + pl < npairs) o4[fi4] = v;
  }
}

extern "C" void kernel_launch(void* const* d_in, const int* in_sizes, int n_in,
                              void* d_out, int out_size, void* d_ws, size_t ws_size,
                              hipStream_t stream) {
  const float* x = (const float*)d_in[0];
  const float* noise = (const float*)d_in[1];
  float* out = (float*)d_out;
  const int npairs = in_sizes[0];  // 1,048,576

  if (ws_size >= (size_t)npairs) {
    unsigned char* lat = (unsigned char*)d_ws;
    if ((npairs & 3) == 0) {
      lat_kernel_v4<<<512, 256, 0, stream>>>((const float4*)x, (const float4*)noise,
                                             (uchar4*)lat, npairs / 4);
    } else {
      lat_kernel_scalar<<<1024, 256, 0, stream>>>(x, noise, lat, npairs);
    }
    const int n4 = out_size / 4;  // 26,214,400
    onehot_stream_kernel<<<2048, 256, 0, stream>>>(lat, (vf4*)out, n4);
  } else {
    const int grid = (npairs + 255) / 256;
    latency_encode_fused<<<grid, 256, 0, stream>>>(x, noise, out, npairs);
  }
}